// Round 5
// baseline (157.731 us; speedup 1.0000x reference)
//
#include <hip/hip_runtime.h>
#include <hip/hip_bf16.h>

// HybridBCEDiceBoundaryLoss — scalar loss over logits/targets (32,1,512,512) fp32.
// loss = 0.3*BCE + 0.3*Dice + 0.2*BoundaryBCE + 0.2*LovaszHinge(per-image mean)
//
// Lovasz without sorting: counts-only histogram over e in (0,8), 1024 bins,
// suffix-scan ranks, bin-midpoint values (2nd-order accurate).
//
// R5: wave = 4 rows x 256 cols (was 8x256) -> 8192 waves (32/CU) for latency
// hiding; __launch_bounds__(256,8) to cap VGPR at 64. BPI 32->64 (2048 blocks).

#define NB      32
#define HH      512
#define WW      512
#define HW      (HH*WW)          // 262144
#define NTOT    (NB*HW)          // 8388608
#define K_BINS  1024
#define INV_H   128.0f           // K_BINS / 8.0 range
#define BIN_W   (1.0f/128.0f)
#define BPI     64               // blocks per image; block = 8 rows x 512 cols

struct Ws {
    unsigned cnt[NB*K_BINS];      // low16 = count_all, high16 = count_pos
    float    sy[NB];
    float    spy[NB];
    float    Pim[NB];
    float    bce_sum;
    float    bceE_sum;
    float    lov_sum;
};

__device__ __forceinline__ void process_elem(float x, float y, float wsum,
                                             float& bce_s, float& bceE_s, float& sy_s,
                                             float& spy_s, float& P_s,
                                             unsigned* s_cnt) {
    const float ax = fabsf(x);
    const float t  = __expf(-ax);                       // exp(-|x|)
    const float bce = fmaxf(x, 0.f) - x * y + __logf(1.f + t);
    const float inv = __builtin_amdgcn_rcpf(1.f + t);
    const float s = (x >= 0.f) ? inv : t * inv;         // sigmoid(x)
    const bool edge = (wsum > 0.5f) && (wsum < 8.5f);   // 1..8 of 9 ones

    bce_s  += bce;
    bceE_s += edge ? bce : 0.f;
    sy_s   += s * y;
    spy_s  += s + y;
    P_s    += y;

    const float e = 1.f - x * (2.f * y - 1.f);
    if (e > 0.f) {
        int b = (int)(e * INV_H);
        if (b > K_BINS - 1) b = K_BINS - 1;
        atomicAdd(&s_cnt[b], (y > 0.5f) ? 0x10001u : 1u);
    }
}

__global__ __launch_bounds__(256, 8) void kernelA(const float* __restrict__ logits,
                                                  const float* __restrict__ targets,
                                                  Ws* __restrict__ ws) {
    __shared__ unsigned s_cnt[K_BINS];
    __shared__ float    s_bL[2][4];   // col-255 triple-sums (written by half0 lane63)
    __shared__ float    s_bR[2][4];   // col-256 triple-sums (written by half1 lane0)
    __shared__ float    red[4][5];

    const int tid   = threadIdx.x;
    const int lane  = tid & 63;
    const int wave  = tid >> 6;
    const int half  = wave & 1;       // 0 = cols 0..255, 1 = cols 256..511
    const int strip = wave >> 1;      // 0 = rows r0..r0+3, 1 = rows r0+4..r0+7

    for (int i = tid; i < K_BINS; i += 256) s_cnt[i] = 0u;

    const int img = blockIdx.x >> 6;
    const int blk = blockIdx.x & 63;
    const int r0  = blk * 8 + strip * 4;        // first output row of this wave
    const int c4  = half * 64 + lane;           // float4 column index 0..127

    const float4* __restrict__ tg4 = (const float4*)(targets + img * HW);
    const float4* __restrict__ lg4 = (const float4*)(logits + img * HW);

    // load 6 target rows: r0-1 .. r0+4
    float4 T[6];
#pragma unroll
    for (int j = 0; j < 6; ++j) {
        const int row = r0 - 1 + j;
        T[j] = (row >= 0 && row < HH) ? tg4[row * 128 + c4]
                                      : make_float4(0.f, 0.f, 0.f, 0.f);
    }

    // publish boundary column triple-sums for the other half-wave
    if (half == 0 && lane == 63) {
#pragma unroll
        for (int j = 0; j < 4; ++j) s_bL[strip][j] = T[j].w + T[j + 1].w + T[j + 2].w;
    }
    if (half == 1 && lane == 0) {
#pragma unroll
        for (int j = 0; j < 4; ++j) s_bR[strip][j] = T[j].x + T[j + 1].x + T[j + 2].x;
    }
    __syncthreads();

    float bce_s = 0.f, bceE_s = 0.f, sy_s = 0.f, spy_s = 0.f, P_s = 0.f;

#pragma unroll
    for (int j = 0; j < 4; ++j) {
        const float4 X = lg4[(r0 + j) * 128 + c4];

        const float cs0 = T[j].x + T[j + 1].x + T[j + 2].x;
        const float cs1 = T[j].y + T[j + 1].y + T[j + 2].y;
        const float cs2 = T[j].z + T[j + 1].z + T[j + 2].z;
        const float cs3 = T[j].w + T[j + 1].w + T[j + 2].w;

        const float upL = __shfl_up(cs3, 1);
        const float dnR = __shfl_down(cs0, 1);
        const float csL = (lane == 0)  ? (half ? s_bL[strip][j] : 0.f) : upL;
        const float csR = (lane == 63) ? (half ? 0.f : s_bR[strip][j]) : dnR;

        const float w0 = csL + cs0 + cs1;
        const float w1 = cs0 + cs1 + cs2;
        const float w2 = cs1 + cs2 + cs3;
        const float w3 = cs2 + cs3 + csR;

        process_elem(X.x, T[j + 1].x, w0, bce_s, bceE_s, sy_s, spy_s, P_s, s_cnt);
        process_elem(X.y, T[j + 1].y, w1, bce_s, bceE_s, sy_s, spy_s, P_s, s_cnt);
        process_elem(X.z, T[j + 1].z, w2, bce_s, bceE_s, sy_s, spy_s, P_s, s_cnt);
        process_elem(X.w, T[j + 1].w, w3, bce_s, bceE_s, sy_s, spy_s, P_s, s_cnt);
    }
    __syncthreads();

    // flush histogram to global (packed counts)
    unsigned* g_c = ws->cnt + img * K_BINS;
    for (int i = tid; i < K_BINS; i += 256) {
        const unsigned cpk = s_cnt[i];
        if (cpk) atomicAdd(&g_c[i], cpk);
    }

    // block reduction of 5 accumulators
    for (int off = 32; off; off >>= 1) {
        bce_s  += __shfl_down(bce_s, off);
        bceE_s += __shfl_down(bceE_s, off);
        sy_s   += __shfl_down(sy_s, off);
        spy_s  += __shfl_down(spy_s, off);
        P_s    += __shfl_down(P_s, off);
    }
    if (lane == 0) {
        red[wave][0] = bce_s; red[wave][1] = bceE_s; red[wave][2] = sy_s;
        red[wave][3] = spy_s; red[wave][4] = P_s;
    }
    __syncthreads();
    if (tid == 0) {
        float a = 0.f, b = 0.f, c2 = 0.f, d = 0.f, e2 = 0.f;
        for (int w = 0; w < 4; ++w) {
            a += red[w][0]; b += red[w][1]; c2 += red[w][2];
            d += red[w][3]; e2 += red[w][4];
        }
        atomicAdd(&ws->bce_sum, a);
        atomicAdd(&ws->bceE_sum, b);
        atomicAdd(&ws->sy[img], c2);
        atomicAdd(&ws->spy[img], d);
        atomicAdd(&ws->Pim[img], e2);
    }
}

__global__ __launch_bounds__(256) void kernelB(Ws* __restrict__ ws) {
    __shared__ unsigned sc_a[256];
    __shared__ unsigned sc_p[256];
    __shared__ double   dred[4];

    const int img = blockIdx.x;
    const int tid = threadIdx.x;
    const unsigned* __restrict__ cn = ws->cnt + img * K_BINS;

    // each thread handles 4 bins in descending-bin order
    unsigned la[4], lp[4];
    float    me[4];
    unsigned tot_a = 0, tot_p = 0;
#pragma unroll
    for (int j = 0; j < 4; ++j) {
        const int k = K_BINS - 1 - (tid * 4 + j);
        const unsigned cpk = cn[k];
        la[j] = cpk & 0xFFFFu; lp[j] = cpk >> 16;
        me[j] = ((float)k + 0.5f) * BIN_W;          // bin-midpoint error value
        tot_a += la[j]; tot_p += lp[j];
    }

    // block-wide inclusive scan of per-thread totals
    sc_a[tid] = tot_a; sc_p[tid] = tot_p;
    __syncthreads();
    for (int off = 1; off < 256; off <<= 1) {
        unsigned va = (tid >= off) ? sc_a[tid - off] : 0u;
        unsigned vp = (tid >= off) ? sc_p[tid - off] : 0u;
        __syncthreads();
        sc_a[tid] += va; sc_p[tid] += vp;
        __syncthreads();
    }
    const unsigned excl_a = sc_a[tid] - tot_a;
    const unsigned excl_p = sc_p[tid] - tot_p;

    const double P = (double)ws->Pim[img];
    double run_a = (double)excl_a, run_p = (double)excl_p;
    double contrib = 0.0;
#pragma unroll
    for (int j = 0; j < 4; ++j) {
        const double m = (double)la[j];
        const double p = (double)lp[j];
        if (la[j]) {
            const double u = P + (run_a + 0.5 * m) - (run_p + 0.5 * p);
            const double c = run_p + 0.5 * p;
            contrib += (double)(lp[j] * me[j]) / u;                  // positives: dJ = 1/u
            const double den = u * (u - 1.0);
            if (den > 0.0)
                contrib += (double)((la[j] - lp[j]) * me[j]) * (P - c) / den;  // negatives
        }
        run_a += m; run_p += p;
    }

    for (int off = 32; off; off >>= 1) contrib += __shfl_down(contrib, off);
    const int wave = tid >> 6;
    const int lane = tid & 63;
    if (lane == 0) dred[wave] = contrib;
    __syncthreads();
    if (tid == 0) {
        double tot = dred[0] + dred[1] + dred[2] + dred[3];
        atomicAdd(&ws->lov_sum, (float)tot);
    }
}

__global__ __launch_bounds__(64) void kernelC(const Ws* __restrict__ ws,
                                              float* __restrict__ out) {
    const int lane = threadIdx.x;
    float dsum = 0.f;
    if (lane < NB) {
        const float num = 2.f * ws->sy[lane];
        const float den = ws->spy[lane] + 1e-7f;
        dsum = num / den;
    }
    for (int off = 32; off; off >>= 1) dsum += __shfl_down(dsum, off);
    if (lane == 0) {
        const float invN = 1.f / (float)NTOT;
        const float bce      = ws->bce_sum * invN;
        const float boundary = (ws->bce_sum + 2.f * ws->bceE_sum) * invN;
        const float dice     = 1.f - dsum / (float)NB;
        const float lov      = ws->lov_sum / (float)NB;
        out[0] = 0.3f * bce + 0.3f * dice + 0.2f * boundary + 0.2f * lov;
    }
}

extern "C" void kernel_launch(void* const* d_in, const int* in_sizes, int n_in,
                              void* d_out, int out_size, void* d_ws, size_t ws_size,
                              hipStream_t stream) {
    const float* logits  = (const float*)d_in[0];
    const float* targets = (const float*)d_in[1];
    float* out = (float*)d_out;
    Ws* ws = (Ws*)d_ws;

    (void)hipMemsetAsync(d_ws, 0, sizeof(Ws), stream);
    kernelA<<<NB * BPI, 256, 0, stream>>>(logits, targets, ws);
    kernelB<<<NB, 256, 0, stream>>>(ws);
    kernelC<<<1, 64, 0, stream>>>(ws, out);
}

// Round 6
// 130.484 us; speedup vs baseline: 1.2088x; 1.2088x over previous
//
#include <hip/hip_runtime.h>
#include <hip/hip_bf16.h>

// HybridBCEDiceBoundaryLoss — scalar loss over logits/targets (32,1,512,512) fp32.
// loss = 0.3*BCE + 0.3*Dice + 0.2*BoundaryBCE + 0.2*LovaszHinge(per-image mean)
//
// Lovasz without sorting: counts-only histogram over e in (0,8), 1024 bins,
// suffix-scan ranks, bin-midpoint values (2nd-order accurate).
//
// R6: 512-thread blocks (8 waves), wave = 4 rows x 256 cols -> 8192 waves (32/CU)
// WITHOUT the R5 register squeeze (launch_bounds(512,4); R5's (256,8) forced
// VGPR=32 -> scratch spill, WRITE_SIZE +8.3MB). BPI=32 (1024 blocks) keeps
// histogram flush traffic at R4 levels.

#define NB      32
#define HH      512
#define WW      512
#define HW      (HH*WW)          // 262144
#define NTOT    (NB*HW)          // 8388608
#define K_BINS  1024
#define INV_H   128.0f           // K_BINS / 8.0 range
#define BIN_W   (1.0f/128.0f)
#define BPI     32               // blocks per image; block = 16 rows x 512 cols

struct Ws {
    unsigned cnt[NB*K_BINS];      // low16 = count_all, high16 = count_pos
    float    sy[NB];
    float    spy[NB];
    float    Pim[NB];
    float    bce_sum;
    float    bceE_sum;
    float    lov_sum;
};

__device__ __forceinline__ void process_elem(float x, float y, float wsum,
                                             float& bce_s, float& bceE_s, float& sy_s,
                                             float& spy_s, float& P_s,
                                             unsigned* s_cnt) {
    const float ax = fabsf(x);
    const float t  = __expf(-ax);                       // exp(-|x|)
    const float bce = fmaxf(x, 0.f) - x * y + __logf(1.f + t);
    const float inv = __builtin_amdgcn_rcpf(1.f + t);
    const float s = (x >= 0.f) ? inv : t * inv;         // sigmoid(x)
    const bool edge = (wsum > 0.5f) && (wsum < 8.5f);   // 1..8 of 9 ones

    bce_s  += bce;
    bceE_s += edge ? bce : 0.f;
    sy_s   += s * y;
    spy_s  += s + y;
    P_s    += y;

    const float e = 1.f - x * (2.f * y - 1.f);
    if (e > 0.f) {
        int b = (int)(e * INV_H);
        if (b > K_BINS - 1) b = K_BINS - 1;
        atomicAdd(&s_cnt[b], (y > 0.5f) ? 0x10001u : 1u);
    }
}

__global__ __launch_bounds__(512, 4) void kernelA(const float* __restrict__ logits,
                                                  const float* __restrict__ targets,
                                                  Ws* __restrict__ ws) {
    __shared__ unsigned s_cnt[K_BINS];
    __shared__ float    s_bL[4][4];   // col-255 triple-sums (written by half0 lane63)
    __shared__ float    s_bR[4][4];   // col-256 triple-sums (written by half1 lane0)
    __shared__ float    red[8][5];

    const int tid   = threadIdx.x;
    const int lane  = tid & 63;
    const int wave  = tid >> 6;       // 0..7
    const int half  = wave & 1;       // 0 = cols 0..255, 1 = cols 256..511
    const int strip = wave >> 1;      // 0..3 -> rows r0 = blk*16 + strip*4

    for (int i = tid; i < K_BINS; i += 512) s_cnt[i] = 0u;

    const int img = blockIdx.x >> 5;
    const int blk = blockIdx.x & 31;
    const int r0  = blk * 16 + strip * 4;       // first output row of this wave
    const int c4  = half * 64 + lane;           // float4 column index 0..127

    const float4* __restrict__ tg4 = (const float4*)(targets + img * HW);
    const float4* __restrict__ lg4 = (const float4*)(logits + img * HW);

    // load 6 target rows (r0-1 .. r0+4) and 4 logit rows — 10 loads in flight
    float4 T[6];
#pragma unroll
    for (int j = 0; j < 6; ++j) {
        const int row = r0 - 1 + j;
        T[j] = (row >= 0 && row < HH) ? tg4[row * 128 + c4]
                                      : make_float4(0.f, 0.f, 0.f, 0.f);
    }
    float4 X[4];
#pragma unroll
    for (int j = 0; j < 4; ++j) X[j] = lg4[(r0 + j) * 128 + c4];

    // publish boundary column triple-sums for the other half-wave
    if (half == 0 && lane == 63) {
#pragma unroll
        for (int j = 0; j < 4; ++j) s_bL[strip][j] = T[j].w + T[j + 1].w + T[j + 2].w;
    }
    if (half == 1 && lane == 0) {
#pragma unroll
        for (int j = 0; j < 4; ++j) s_bR[strip][j] = T[j].x + T[j + 1].x + T[j + 2].x;
    }
    __syncthreads();

    float bce_s = 0.f, bceE_s = 0.f, sy_s = 0.f, spy_s = 0.f, P_s = 0.f;

#pragma unroll
    for (int j = 0; j < 4; ++j) {
        const float cs0 = T[j].x + T[j + 1].x + T[j + 2].x;
        const float cs1 = T[j].y + T[j + 1].y + T[j + 2].y;
        const float cs2 = T[j].z + T[j + 1].z + T[j + 2].z;
        const float cs3 = T[j].w + T[j + 1].w + T[j + 2].w;

        const float upL = __shfl_up(cs3, 1);
        const float dnR = __shfl_down(cs0, 1);
        const float csL = (lane == 0)  ? (half ? s_bL[strip][j] : 0.f) : upL;
        const float csR = (lane == 63) ? (half ? 0.f : s_bR[strip][j]) : dnR;

        const float w0 = csL + cs0 + cs1;
        const float w1 = cs0 + cs1 + cs2;
        const float w2 = cs1 + cs2 + cs3;
        const float w3 = cs2 + cs3 + csR;

        process_elem(X[j].x, T[j + 1].x, w0, bce_s, bceE_s, sy_s, spy_s, P_s, s_cnt);
        process_elem(X[j].y, T[j + 1].y, w1, bce_s, bceE_s, sy_s, spy_s, P_s, s_cnt);
        process_elem(X[j].z, T[j + 1].z, w2, bce_s, bceE_s, sy_s, spy_s, P_s, s_cnt);
        process_elem(X[j].w, T[j + 1].w, w3, bce_s, bceE_s, sy_s, spy_s, P_s, s_cnt);
    }
    __syncthreads();

    // flush histogram to global (packed counts)
    unsigned* g_c = ws->cnt + img * K_BINS;
    for (int i = tid; i < K_BINS; i += 512) {
        const unsigned cpk = s_cnt[i];
        if (cpk) atomicAdd(&g_c[i], cpk);
    }

    // block reduction of 5 accumulators
    for (int off = 32; off; off >>= 1) {
        bce_s  += __shfl_down(bce_s, off);
        bceE_s += __shfl_down(bceE_s, off);
        sy_s   += __shfl_down(sy_s, off);
        spy_s  += __shfl_down(spy_s, off);
        P_s    += __shfl_down(P_s, off);
    }
    if (lane == 0) {
        red[wave][0] = bce_s; red[wave][1] = bceE_s; red[wave][2] = sy_s;
        red[wave][3] = spy_s; red[wave][4] = P_s;
    }
    __syncthreads();
    if (tid == 0) {
        float a = 0.f, b = 0.f, c2 = 0.f, d = 0.f, e2 = 0.f;
        for (int w = 0; w < 8; ++w) {
            a += red[w][0]; b += red[w][1]; c2 += red[w][2];
            d += red[w][3]; e2 += red[w][4];
        }
        atomicAdd(&ws->bce_sum, a);
        atomicAdd(&ws->bceE_sum, b);
        atomicAdd(&ws->sy[img], c2);
        atomicAdd(&ws->spy[img], d);
        atomicAdd(&ws->Pim[img], e2);
    }
}

__global__ __launch_bounds__(256) void kernelB(Ws* __restrict__ ws) {
    __shared__ unsigned sc_a[256];
    __shared__ unsigned sc_p[256];
    __shared__ double   dred[4];

    const int img = blockIdx.x;
    const int tid = threadIdx.x;
    const unsigned* __restrict__ cn = ws->cnt + img * K_BINS;

    // each thread handles 4 bins in descending-bin order
    unsigned la[4], lp[4];
    float    me[4];
    unsigned tot_a = 0, tot_p = 0;
#pragma unroll
    for (int j = 0; j < 4; ++j) {
        const int k = K_BINS - 1 - (tid * 4 + j);
        const unsigned cpk = cn[k];
        la[j] = cpk & 0xFFFFu; lp[j] = cpk >> 16;
        me[j] = ((float)k + 0.5f) * BIN_W;          // bin-midpoint error value
        tot_a += la[j]; tot_p += lp[j];
    }

    // block-wide inclusive scan of per-thread totals
    sc_a[tid] = tot_a; sc_p[tid] = tot_p;
    __syncthreads();
    for (int off = 1; off < 256; off <<= 1) {
        unsigned va = (tid >= off) ? sc_a[tid - off] : 0u;
        unsigned vp = (tid >= off) ? sc_p[tid - off] : 0u;
        __syncthreads();
        sc_a[tid] += va; sc_p[tid] += vp;
        __syncthreads();
    }
    const unsigned excl_a = sc_a[tid] - tot_a;
    const unsigned excl_p = sc_p[tid] - tot_p;

    const double P = (double)ws->Pim[img];
    double run_a = (double)excl_a, run_p = (double)excl_p;
    double contrib = 0.0;
#pragma unroll
    for (int j = 0; j < 4; ++j) {
        const double m = (double)la[j];
        const double p = (double)lp[j];
        if (la[j]) {
            const double u = P + (run_a + 0.5 * m) - (run_p + 0.5 * p);
            const double c = run_p + 0.5 * p;
            contrib += (double)(lp[j] * me[j]) / u;                  // positives: dJ = 1/u
            const double den = u * (u - 1.0);
            if (den > 0.0)
                contrib += (double)((la[j] - lp[j]) * me[j]) * (P - c) / den;  // negatives
        }
        run_a += m; run_p += p;
    }

    for (int off = 32; off; off >>= 1) contrib += __shfl_down(contrib, off);
    const int wave = tid >> 6;
    const int lane = tid & 63;
    if (lane == 0) dred[wave] = contrib;
    __syncthreads();
    if (tid == 0) {
        double tot = dred[0] + dred[1] + dred[2] + dred[3];
        atomicAdd(&ws->lov_sum, (float)tot);
    }
}

__global__ __launch_bounds__(64) void kernelC(const Ws* __restrict__ ws,
                                              float* __restrict__ out) {
    const int lane = threadIdx.x;
    float dsum = 0.f;
    if (lane < NB) {
        const float num = 2.f * ws->sy[lane];
        const float den = ws->spy[lane] + 1e-7f;
        dsum = num / den;
    }
    for (int off = 32; off; off >>= 1) dsum += __shfl_down(dsum, off);
    if (lane == 0) {
        const float invN = 1.f / (float)NTOT;
        const float bce      = ws->bce_sum * invN;
        const float boundary = (ws->bce_sum + 2.f * ws->bceE_sum) * invN;
        const float dice     = 1.f - dsum / (float)NB;
        const float lov      = ws->lov_sum / (float)NB;
        out[0] = 0.3f * bce + 0.3f * dice + 0.2f * boundary + 0.2f * lov;
    }
}

extern "C" void kernel_launch(void* const* d_in, const int* in_sizes, int n_in,
                              void* d_out, int out_size, void* d_ws, size_t ws_size,
                              hipStream_t stream) {
    const float* logits  = (const float*)d_in[0];
    const float* targets = (const float*)d_in[1];
    float* out = (float*)d_out;
    Ws* ws = (Ws*)d_ws;

    (void)hipMemsetAsync(d_ws, 0, sizeof(Ws), stream);
    kernelA<<<NB * BPI, 512, 0, stream>>>(logits, targets, ws);
    kernelB<<<NB, 256, 0, stream>>>(ws);
    kernelC<<<1, 64, 0, stream>>>(ws, out);
}

// Round 7
// 129.264 us; speedup vs baseline: 1.2202x; 1.0094x over previous
//
#include <hip/hip_runtime.h>
#include <hip/hip_bf16.h>

// HybridBCEDiceBoundaryLoss — scalar loss over logits/targets (32,1,512,512) fp32.
// loss = 0.3*BCE + 0.3*Dice + 0.2*BoundaryBCE + 0.2*LovaszHinge(per-image mean)
//
// Lovasz without sorting: counts-only histogram over e in (0,8), 1024 bins,
// suffix-scan ranks, bin-midpoint values (2nd-order accurate).
//
// R7: ONLY change vs R6: __launch_bounds__(512,1) — R6's (512,4) capped VGPR at 36,
// which cannot hold the 40 VGPRs of T[6]+X[4] load data; compiler sank loads into
// the compute loop -> ~2 outstanding loads/wave -> latency-bound at ~3 GB/s/CU.
// Freeing the allocator lets all 10 loads issue before the barrier (true MLP).

#define NB      32
#define HH      512
#define WW      512
#define HW      (HH*WW)          // 262144
#define NTOT    (NB*HW)          // 8388608
#define K_BINS  1024
#define INV_H   128.0f           // K_BINS / 8.0 range
#define BIN_W   (1.0f/128.0f)
#define BPI     32               // blocks per image; block = 16 rows x 512 cols

struct Ws {
    unsigned cnt[NB*K_BINS];      // low16 = count_all, high16 = count_pos
    float    sy[NB];
    float    spy[NB];
    float    Pim[NB];
    float    bce_sum;
    float    bceE_sum;
    float    lov_sum;
};

__device__ __forceinline__ void process_elem(float x, float y, float wsum,
                                             float& bce_s, float& bceE_s, float& sy_s,
                                             float& spy_s, float& P_s,
                                             unsigned* s_cnt) {
    const float ax = fabsf(x);
    const float t  = __expf(-ax);                       // exp(-|x|)
    const float bce = fmaxf(x, 0.f) - x * y + __logf(1.f + t);
    const float inv = __builtin_amdgcn_rcpf(1.f + t);
    const float s = (x >= 0.f) ? inv : t * inv;         // sigmoid(x)
    const bool edge = (wsum > 0.5f) && (wsum < 8.5f);   // 1..8 of 9 ones

    bce_s  += bce;
    bceE_s += edge ? bce : 0.f;
    sy_s   += s * y;
    spy_s  += s + y;
    P_s    += y;

    const float e = 1.f - x * (2.f * y - 1.f);
    if (e > 0.f) {
        int b = (int)(e * INV_H);
        if (b > K_BINS - 1) b = K_BINS - 1;
        atomicAdd(&s_cnt[b], (y > 0.5f) ? 0x10001u : 1u);
    }
}

__global__ __launch_bounds__(512, 1) void kernelA(const float* __restrict__ logits,
                                                  const float* __restrict__ targets,
                                                  Ws* __restrict__ ws) {
    __shared__ unsigned s_cnt[K_BINS];
    __shared__ float    s_bL[4][4];   // col-255 triple-sums (written by half0 lane63)
    __shared__ float    s_bR[4][4];   // col-256 triple-sums (written by half1 lane0)
    __shared__ float    red[8][5];

    const int tid   = threadIdx.x;
    const int lane  = tid & 63;
    const int wave  = tid >> 6;       // 0..7
    const int half  = wave & 1;       // 0 = cols 0..255, 1 = cols 256..511
    const int strip = wave >> 1;      // 0..3 -> rows r0 = blk*16 + strip*4

    for (int i = tid; i < K_BINS; i += 512) s_cnt[i] = 0u;

    const int img = blockIdx.x >> 5;
    const int blk = blockIdx.x & 31;
    const int r0  = blk * 16 + strip * 4;       // first output row of this wave
    const int c4  = half * 64 + lane;           // float4 column index 0..127

    const float4* __restrict__ tg4 = (const float4*)(targets + img * HW);
    const float4* __restrict__ lg4 = (const float4*)(logits + img * HW);

    // load 6 target rows (r0-1 .. r0+4) and 4 logit rows — 10 loads in flight
    float4 T[6];
#pragma unroll
    for (int j = 0; j < 6; ++j) {
        const int row = r0 - 1 + j;
        T[j] = (row >= 0 && row < HH) ? tg4[row * 128 + c4]
                                      : make_float4(0.f, 0.f, 0.f, 0.f);
    }
    float4 X[4];
#pragma unroll
    for (int j = 0; j < 4; ++j) X[j] = lg4[(r0 + j) * 128 + c4];

    // publish boundary column triple-sums for the other half-wave
    if (half == 0 && lane == 63) {
#pragma unroll
        for (int j = 0; j < 4; ++j) s_bL[strip][j] = T[j].w + T[j + 1].w + T[j + 2].w;
    }
    if (half == 1 && lane == 0) {
#pragma unroll
        for (int j = 0; j < 4; ++j) s_bR[strip][j] = T[j].x + T[j + 1].x + T[j + 2].x;
    }
    __syncthreads();

    float bce_s = 0.f, bceE_s = 0.f, sy_s = 0.f, spy_s = 0.f, P_s = 0.f;

#pragma unroll
    for (int j = 0; j < 4; ++j) {
        const float cs0 = T[j].x + T[j + 1].x + T[j + 2].x;
        const float cs1 = T[j].y + T[j + 1].y + T[j + 2].y;
        const float cs2 = T[j].z + T[j + 1].z + T[j + 2].z;
        const float cs3 = T[j].w + T[j + 1].w + T[j + 2].w;

        const float upL = __shfl_up(cs3, 1);
        const float dnR = __shfl_down(cs0, 1);
        const float csL = (lane == 0)  ? (half ? s_bL[strip][j] : 0.f) : upL;
        const float csR = (lane == 63) ? (half ? 0.f : s_bR[strip][j]) : dnR;

        const float w0 = csL + cs0 + cs1;
        const float w1 = cs0 + cs1 + cs2;
        const float w2 = cs1 + cs2 + cs3;
        const float w3 = cs2 + cs3 + csR;

        process_elem(X[j].x, T[j + 1].x, w0, bce_s, bceE_s, sy_s, spy_s, P_s, s_cnt);
        process_elem(X[j].y, T[j + 1].y, w1, bce_s, bceE_s, sy_s, spy_s, P_s, s_cnt);
        process_elem(X[j].z, T[j + 1].z, w2, bce_s, bceE_s, sy_s, spy_s, P_s, s_cnt);
        process_elem(X[j].w, T[j + 1].w, w3, bce_s, bceE_s, sy_s, spy_s, P_s, s_cnt);
    }
    __syncthreads();

    // flush histogram to global (packed counts)
    unsigned* g_c = ws->cnt + img * K_BINS;
    for (int i = tid; i < K_BINS; i += 512) {
        const unsigned cpk = s_cnt[i];
        if (cpk) atomicAdd(&g_c[i], cpk);
    }

    // block reduction of 5 accumulators
    for (int off = 32; off; off >>= 1) {
        bce_s  += __shfl_down(bce_s, off);
        bceE_s += __shfl_down(bceE_s, off);
        sy_s   += __shfl_down(sy_s, off);
        spy_s  += __shfl_down(spy_s, off);
        P_s    += __shfl_down(P_s, off);
    }
    if (lane == 0) {
        red[wave][0] = bce_s; red[wave][1] = bceE_s; red[wave][2] = sy_s;
        red[wave][3] = spy_s; red[wave][4] = P_s;
    }
    __syncthreads();
    if (tid == 0) {
        float a = 0.f, b = 0.f, c2 = 0.f, d = 0.f, e2 = 0.f;
        for (int w = 0; w < 8; ++w) {
            a += red[w][0]; b += red[w][1]; c2 += red[w][2];
            d += red[w][3]; e2 += red[w][4];
        }
        atomicAdd(&ws->bce_sum, a);
        atomicAdd(&ws->bceE_sum, b);
        atomicAdd(&ws->sy[img], c2);
        atomicAdd(&ws->spy[img], d);
        atomicAdd(&ws->Pim[img], e2);
    }
}

__global__ __launch_bounds__(256) void kernelB(Ws* __restrict__ ws) {
    __shared__ unsigned sc_a[256];
    __shared__ unsigned sc_p[256];
    __shared__ double   dred[4];

    const int img = blockIdx.x;
    const int tid = threadIdx.x;
    const unsigned* __restrict__ cn = ws->cnt + img * K_BINS;

    // each thread handles 4 bins in descending-bin order
    unsigned la[4], lp[4];
    float    me[4];
    unsigned tot_a = 0, tot_p = 0;
#pragma unroll
    for (int j = 0; j < 4; ++j) {
        const int k = K_BINS - 1 - (tid * 4 + j);
        const unsigned cpk = cn[k];
        la[j] = cpk & 0xFFFFu; lp[j] = cpk >> 16;
        me[j] = ((float)k + 0.5f) * BIN_W;          // bin-midpoint error value
        tot_a += la[j]; tot_p += lp[j];
    }

    // block-wide inclusive scan of per-thread totals
    sc_a[tid] = tot_a; sc_p[tid] = tot_p;
    __syncthreads();
    for (int off = 1; off < 256; off <<= 1) {
        unsigned va = (tid >= off) ? sc_a[tid - off] : 0u;
        unsigned vp = (tid >= off) ? sc_p[tid - off] : 0u;
        __syncthreads();
        sc_a[tid] += va; sc_p[tid] += vp;
        __syncthreads();
    }
    const unsigned excl_a = sc_a[tid] - tot_a;
    const unsigned excl_p = sc_p[tid] - tot_p;

    const double P = (double)ws->Pim[img];
    double run_a = (double)excl_a, run_p = (double)excl_p;
    double contrib = 0.0;
#pragma unroll
    for (int j = 0; j < 4; ++j) {
        const double m = (double)la[j];
        const double p = (double)lp[j];
        if (la[j]) {
            const double u = P + (run_a + 0.5 * m) - (run_p + 0.5 * p);
            const double c = run_p + 0.5 * p;
            contrib += (double)(lp[j] * me[j]) / u;                  // positives: dJ = 1/u
            const double den = u * (u - 1.0);
            if (den > 0.0)
                contrib += (double)((la[j] - lp[j]) * me[j]) * (P - c) / den;  // negatives
        }
        run_a += m; run_p += p;
    }

    for (int off = 32; off; off >>= 1) contrib += __shfl_down(contrib, off);
    const int wave = tid >> 6;
    const int lane = tid & 63;
    if (lane == 0) dred[wave] = contrib;
    __syncthreads();
    if (tid == 0) {
        double tot = dred[0] + dred[1] + dred[2] + dred[3];
        atomicAdd(&ws->lov_sum, (float)tot);
    }
}

__global__ __launch_bounds__(64) void kernelC(const Ws* __restrict__ ws,
                                              float* __restrict__ out) {
    const int lane = threadIdx.x;
    float dsum = 0.f;
    if (lane < NB) {
        const float num = 2.f * ws->sy[lane];
        const float den = ws->spy[lane] + 1e-7f;
        dsum = num / den;
    }
    for (int off = 32; off; off >>= 1) dsum += __shfl_down(dsum, off);
    if (lane == 0) {
        const float invN = 1.f / (float)NTOT;
        const float bce      = ws->bce_sum * invN;
        const float boundary = (ws->bce_sum + 2.f * ws->bceE_sum) * invN;
        const float dice     = 1.f - dsum / (float)NB;
        const float lov      = ws->lov_sum / (float)NB;
        out[0] = 0.3f * bce + 0.3f * dice + 0.2f * boundary + 0.2f * lov;
    }
}

extern "C" void kernel_launch(void* const* d_in, const int* in_sizes, int n_in,
                              void* d_out, int out_size, void* d_ws, size_t ws_size,
                              hipStream_t stream) {
    const float* logits  = (const float*)d_in[0];
    const float* targets = (const float*)d_in[1];
    float* out = (float*)d_out;
    Ws* ws = (Ws*)d_ws;

    (void)hipMemsetAsync(d_ws, 0, sizeof(Ws), stream);
    kernelA<<<NB * BPI, 512, 0, stream>>>(logits, targets, ws);
    kernelB<<<NB, 256, 0, stream>>>(ws);
    kernelC<<<1, 64, 0, stream>>>(ws, out);
}

// Round 8
// 116.054 us; speedup vs baseline: 1.3591x; 1.1138x over previous
//
#include <hip/hip_runtime.h>
#include <hip/hip_bf16.h>

// HybridBCEDiceBoundaryLoss — scalar loss over logits/targets (32,1,512,512) fp32.
// loss = 0.3*BCE + 0.3*Dice + 0.2*BoundaryBCE + 0.2*LovaszHinge(per-image mean)
//
// Lovasz without sorting: counts-only histogram over e in (0,8), 1024 bins,
// suffix-scan ranks, bin-midpoint values (2nd-order accurate).
//
// R8: branchless rolling-window streaming. R7 falsified the launch-bounds theory
// (VGPR stayed 36): the real blocker is branch-GUARDED halo loads — per-BB
// scheduling keeps loads sunk, ~2 in flight/CU -> 43us of exposed latency.
// Now: wave = full 512-col row strip (2 coalesced 1KB loads/row), 8-row loop,
// circular T[5]/X[3] register windows, clamp+flag (no branches) for image edges,
// explicit prefetch 3 steps ahead, zero in-loop barriers.

#define NB      32
#define HH      512
#define WW      512
#define HW      (HH*WW)          // 262144
#define NTOT    (NB*HW)          // 8388608
#define K_BINS  1024
#define INV_H   128.0f           // K_BINS / 8.0 range
#define BIN_W   (1.0f/128.0f)

struct Ws {
    unsigned cnt[NB*K_BINS];      // low16 = count_all, high16 = count_pos
    float    sy[NB];
    float    spy[NB];
    float    Pim[NB];
    float    bce_sum;
    float    bceE_sum;
    float    lov_sum;
};

__device__ __forceinline__ void process_elem(float x, float y, float wsum,
                                             float& bce_s, float& bceE_s, float& sy_s,
                                             float& spy_s, float& P_s,
                                             unsigned* s_cnt) {
    const float ax = fabsf(x);
    const float t  = __expf(-ax);                       // exp(-|x|)
    const float bce = fmaxf(x, 0.f) - x * y + __logf(1.f + t);
    const float inv = __builtin_amdgcn_rcpf(1.f + t);
    const float s = (x >= 0.f) ? inv : t * inv;         // sigmoid(x)
    const bool edge = (wsum > 0.5f) && (wsum < 8.5f);   // 1..8 of 9 ones

    bce_s  += bce;
    bceE_s += edge ? bce : 0.f;
    sy_s   += s * y;
    spy_s  += s + y;
    P_s    += y;

    const float e = 1.f - x * (2.f * y - 1.f);
    if (e > 0.f) {
        int b = (int)(e * INV_H);
        if (b > K_BINS - 1) b = K_BINS - 1;
        atomicAdd(&s_cnt[b], (y > 0.5f) ? 0x10001u : 1u);
    }
}

__global__ __launch_bounds__(256, 2) void kernelA(const float* __restrict__ logits,
                                                  const float* __restrict__ targets,
                                                  Ws* __restrict__ ws) {
    __shared__ unsigned s_cnt[K_BINS];
    __shared__ float    red[4][5];

    const int tid  = threadIdx.x;
    const int lane = tid & 63;
    const int wave = tid >> 6;
    for (int i = tid; i < K_BINS; i += 256) s_cnt[i] = 0u;
    __syncthreads();

    const int img   = blockIdx.x >> 4;                   // 16 blocks per image
    const int strip = ((blockIdx.x & 15) << 2) | wave;   // 0..63
    const int r0    = strip * 8;                         // this wave: rows r0..r0+7

    const float4* __restrict__ tg4 = (const float4*)(targets + img * HW);
    const float4* __restrict__ lg4 = (const float4*)(logits  + img * HW);
    const int cA = lane;         // f4 cols 4*lane   .. 4*lane+3
    const int cB = 64 + lane;    // f4 cols 256+4*lane ..

    // circular windows: T rows r-1..r+1 live in slots (j)%5,(j+1)%5,(j+2)%5
    float4 T[5][2]; float fT[5];
    float4 X[3][2];

#pragma unroll
    for (int s = 0; s < 5; ++s) {                        // rows r0-1 .. r0+3
        const int rr = r0 - 1 + s;
        const int rc = rr < 0 ? 0 : (rr > 511 ? 511 : rr);
        fT[s] = (rr >= 0 && rr < 512) ? 1.f : 0.f;
        T[s][0] = tg4[rc * 128 + cA];
        T[s][1] = tg4[rc * 128 + cB];
    }
#pragma unroll
    for (int s = 0; s < 3; ++s) {                        // logit rows r0 .. r0+2
        const int rr = r0 + s;
        X[s][0] = lg4[rr * 128 + cA];
        X[s][1] = lg4[rr * 128 + cB];
    }

    float bce_s = 0.f, bceE_s = 0.f, sy_s = 0.f, spy_s = 0.f, P_s = 0.f;

#pragma unroll
    for (int j = 0; j < 8; ++j) {
        const int ia = j % 5, ib = (j + 1) % 5, ic = (j + 2) % 5;
        const int xs = j % 3;
        const float fa = fT[ia], fc = fT[ic];

        // column triple-sums for cols 4*lane.. (chunk A) and 256+4*lane.. (chunk B)
        float4 csA, csB;
        csA.x = fmaf(T[ia][0].x, fa, fmaf(T[ic][0].x, fc, T[ib][0].x));
        csA.y = fmaf(T[ia][0].y, fa, fmaf(T[ic][0].y, fc, T[ib][0].y));
        csA.z = fmaf(T[ia][0].z, fa, fmaf(T[ic][0].z, fc, T[ib][0].z));
        csA.w = fmaf(T[ia][0].w, fa, fmaf(T[ic][0].w, fc, T[ib][0].w));
        csB.x = fmaf(T[ia][1].x, fa, fmaf(T[ic][1].x, fc, T[ib][1].x));
        csB.y = fmaf(T[ia][1].y, fa, fmaf(T[ic][1].y, fc, T[ib][1].y));
        csB.z = fmaf(T[ia][1].z, fa, fmaf(T[ic][1].z, fc, T[ib][1].z));
        csB.w = fmaf(T[ia][1].w, fa, fmaf(T[ic][1].w, fc, T[ib][1].w));

        // neighbor columns via shuffles (wave owns the full 512-col row)
        const float upA  = __shfl_up(csA.w, 1);
        const float dnA  = __shfl_down(csA.x, 1);
        const float upB  = __shfl_up(csB.w, 1);
        const float dnB  = __shfl_down(csB.x, 1);
        const float bc0  = __shfl(csB.x, 0);    // col 256 triple-sum
        const float bc63 = __shfl(csA.w, 63);   // col 255 triple-sum
        const float LA = (lane == 0)  ? 0.f  : upA;
        const float RA = (lane == 63) ? bc0  : dnA;
        const float LB = (lane == 0)  ? bc63 : upB;
        const float RB = (lane == 63) ? 0.f  : dnB;

        process_elem(X[xs][0].x, T[ib][0].x, LA + csA.x + csA.y,    bce_s, bceE_s, sy_s, spy_s, P_s, s_cnt);
        process_elem(X[xs][0].y, T[ib][0].y, csA.x + csA.y + csA.z, bce_s, bceE_s, sy_s, spy_s, P_s, s_cnt);
        process_elem(X[xs][0].z, T[ib][0].z, csA.y + csA.z + csA.w, bce_s, bceE_s, sy_s, spy_s, P_s, s_cnt);
        process_elem(X[xs][0].w, T[ib][0].w, csA.z + csA.w + RA,    bce_s, bceE_s, sy_s, spy_s, P_s, s_cnt);
        process_elem(X[xs][1].x, T[ib][1].x, LB + csB.x + csB.y,    bce_s, bceE_s, sy_s, spy_s, P_s, s_cnt);
        process_elem(X[xs][1].y, T[ib][1].y, csB.x + csB.y + csB.z, bce_s, bceE_s, sy_s, spy_s, P_s, s_cnt);
        process_elem(X[xs][1].z, T[ib][1].z, csB.y + csB.z + csB.w, bce_s, bceE_s, sy_s, spy_s, P_s, s_cnt);
        process_elem(X[xs][1].w, T[ib][1].w, csB.z + csB.w + RB,    bce_s, bceE_s, sy_s, spy_s, P_s, s_cnt);

        // prefetch (compile-time pruned; distance = 3 steps)
        if (j < 5) {
            const int rr = r0 + j + 4;                   // target row, may be 512 at last strip
            const int rc = rr > 511 ? 511 : rr;
            fT[ia] = (rr < 512) ? 1.f : 0.f;
            T[ia][0] = tg4[rc * 128 + cA];
            T[ia][1] = tg4[rc * 128 + cB];
            const int rx = r0 + j + 3;                   // logit row, always <= 511
            X[xs][0] = lg4[rx * 128 + cA];
            X[xs][1] = lg4[rx * 128 + cB];
        }
    }
    __syncthreads();

    // flush histogram to global (packed counts)
    unsigned* g_c = ws->cnt + img * K_BINS;
    for (int i = tid; i < K_BINS; i += 256) {
        const unsigned cpk = s_cnt[i];
        if (cpk) atomicAdd(&g_c[i], cpk);
    }

    // block reduction of 5 accumulators
    for (int off = 32; off; off >>= 1) {
        bce_s  += __shfl_down(bce_s, off);
        bceE_s += __shfl_down(bceE_s, off);
        sy_s   += __shfl_down(sy_s, off);
        spy_s  += __shfl_down(spy_s, off);
        P_s    += __shfl_down(P_s, off);
    }
    if (lane == 0) {
        red[wave][0] = bce_s; red[wave][1] = bceE_s; red[wave][2] = sy_s;
        red[wave][3] = spy_s; red[wave][4] = P_s;
    }
    __syncthreads();
    if (tid == 0) {
        float a = 0.f, b = 0.f, c2 = 0.f, d = 0.f, e2 = 0.f;
        for (int w = 0; w < 4; ++w) {
            a += red[w][0]; b += red[w][1]; c2 += red[w][2];
            d += red[w][3]; e2 += red[w][4];
        }
        atomicAdd(&ws->bce_sum, a);
        atomicAdd(&ws->bceE_sum, b);
        atomicAdd(&ws->sy[img], c2);
        atomicAdd(&ws->spy[img], d);
        atomicAdd(&ws->Pim[img], e2);
    }
}

__global__ __launch_bounds__(256) void kernelB(Ws* __restrict__ ws) {
    __shared__ unsigned sc_a[256];
    __shared__ unsigned sc_p[256];
    __shared__ double   dred[4];

    const int img = blockIdx.x;
    const int tid = threadIdx.x;
    const unsigned* __restrict__ cn = ws->cnt + img * K_BINS;

    // each thread handles 4 bins in descending-bin order
    unsigned la[4], lp[4];
    float    me[4];
    unsigned tot_a = 0, tot_p = 0;
#pragma unroll
    for (int j = 0; j < 4; ++j) {
        const int k = K_BINS - 1 - (tid * 4 + j);
        const unsigned cpk = cn[k];
        la[j] = cpk & 0xFFFFu; lp[j] = cpk >> 16;
        me[j] = ((float)k + 0.5f) * BIN_W;          // bin-midpoint error value
        tot_a += la[j]; tot_p += lp[j];
    }

    // block-wide inclusive scan of per-thread totals
    sc_a[tid] = tot_a; sc_p[tid] = tot_p;
    __syncthreads();
    for (int off = 1; off < 256; off <<= 1) {
        unsigned va = (tid >= off) ? sc_a[tid - off] : 0u;
        unsigned vp = (tid >= off) ? sc_p[tid - off] : 0u;
        __syncthreads();
        sc_a[tid] += va; sc_p[tid] += vp;
        __syncthreads();
    }
    const unsigned excl_a = sc_a[tid] - tot_a;
    const unsigned excl_p = sc_p[tid] - tot_p;

    const double P = (double)ws->Pim[img];
    double run_a = (double)excl_a, run_p = (double)excl_p;
    double contrib = 0.0;
#pragma unroll
    for (int j = 0; j < 4; ++j) {
        const double m = (double)la[j];
        const double p = (double)lp[j];
        if (la[j]) {
            const double u = P + (run_a + 0.5 * m) - (run_p + 0.5 * p);
            const double c = run_p + 0.5 * p;
            contrib += (double)(lp[j] * me[j]) / u;                  // positives: dJ = 1/u
            const double den = u * (u - 1.0);
            if (den > 0.0)
                contrib += (double)((la[j] - lp[j]) * me[j]) * (P - c) / den;  // negatives
        }
        run_a += m; run_p += p;
    }

    for (int off = 32; off; off >>= 1) contrib += __shfl_down(contrib, off);
    const int wave = tid >> 6;
    const int lane = tid & 63;
    if (lane == 0) dred[wave] = contrib;
    __syncthreads();
    if (tid == 0) {
        double tot = dred[0] + dred[1] + dred[2] + dred[3];
        atomicAdd(&ws->lov_sum, (float)tot);
    }
}

__global__ __launch_bounds__(64) void kernelC(const Ws* __restrict__ ws,
                                              float* __restrict__ out) {
    const int lane = threadIdx.x;
    float dsum = 0.f;
    if (lane < NB) {
        const float num = 2.f * ws->sy[lane];
        const float den = ws->spy[lane] + 1e-7f;
        dsum = num / den;
    }
    for (int off = 32; off; off >>= 1) dsum += __shfl_down(dsum, off);
    if (lane == 0) {
        const float invN = 1.f / (float)NTOT;
        const float bce      = ws->bce_sum * invN;
        const float boundary = (ws->bce_sum + 2.f * ws->bceE_sum) * invN;
        const float dice     = 1.f - dsum / (float)NB;
        const float lov      = ws->lov_sum / (float)NB;
        out[0] = 0.3f * bce + 0.3f * dice + 0.2f * boundary + 0.2f * lov;
    }
}

extern "C" void kernel_launch(void* const* d_in, const int* in_sizes, int n_in,
                              void* d_out, int out_size, void* d_ws, size_t ws_size,
                              hipStream_t stream) {
    const float* logits  = (const float*)d_in[0];
    const float* targets = (const float*)d_in[1];
    float* out = (float*)d_out;
    Ws* ws = (Ws*)d_ws;

    (void)hipMemsetAsync(d_ws, 0, sizeof(Ws), stream);
    kernelA<<<NB * 16, 256, 0, stream>>>(logits, targets, ws);
    kernelB<<<NB, 256, 0, stream>>>(ws);
    kernelC<<<1, 64, 0, stream>>>(ws, out);
}